// Round 9
// baseline (18.494 us; speedup 1.0000x reference)
//
#include <hip/hip_runtime.h>

#define GB 64
#define GN 128
#define F_OBS 64
#define F_TOT 80
#define ISPLIT 64
#define IPB (GN / ISPLIT)   // 2 i-rows per block

// R8's structure (16.0us) with ONE change: ISPLIT 32->64 (4096 blocks x 2
// waves = 16 blocks/CU = 8 waves/SIMD, the occupancy cap) to hide the
// remaining per-lane load latency. __launch_bounds__(128,8) pins the
// allocator to the 64-VGPR budget that 8 waves/SIMD requires (k-outer body
// measured ~28-52 VGPR in R4/R6, fits).
//
// Standing lessons: no cross-block ordering (R2: 7x), no probs atomics/memset
// (R5), partner rows on the scalar pipe only (R7: per-lane gathers = 8x HBM
// fetch), k-outer + small acc to avoid own-row remat (R4/R6), occupancy is
// the binding constraint (R8: 2->4 waves/SIMD = -2.9us).
__global__ __launch_bounds__(128, 8) void glcn_main(
    const float* __restrict__ h, const float* __restrict__ w,
    float* __restrict__ Aout, float* __restrict__ part) {
  const int blk = blockIdx.x;
  const int b  = blk >> 6;                    // / ISPLIT
  const int q  = blk & (ISPLIT - 1);          // i-split index
  const int is = q * IPB;                     // block-uniform
  const int j  = threadIdx.x;                 // 0..127

  const float* rowj = h + ((size_t)(b * GN + j)) * F_TOT;    // per-lane
  const float* rows = h + ((size_t)(b * GN + is)) * F_TOT;   // uniform->s_load

  float acc[IPB];
#pragma unroll
  for (int ii = 0; ii < IPB; ++ii) acc[ii] = 0.f;

#pragma unroll 4
  for (int kq = 0; kq < F_OBS / 4; ++kq) {
    const float4 hv = *reinterpret_cast<const float4*>(rowj + 4 * kq);
    const float4 wv = *reinterpret_cast<const float4*>(w + 4 * kq);  // scalar
#pragma unroll
    for (int ii = 0; ii < IPB; ++ii) {
      const float* ri = rows + ii * F_TOT + 4 * kq;   // scalar dwordx4
      acc[ii] = fmaf(wv.x, fabsf(hv.x - ri[0]), acc[ii]);
      acc[ii] = fmaf(wv.y, fabsf(hv.y - ri[1]), acc[ii]);
      acc[ii] = fmaf(wv.z, fabsf(hv.z - ri[2]), acc[ii]);
      acc[ii] = fmaf(wv.w, fabsf(hv.w - ri[3]), acc[ii]);
    }
  }

  // Epilogue. sigmoid(x)>0.5 <=> x>0; selected = A?y:(1-y) = sigmoid(|x|).
  float logsum = 0.f;
  float* Abase = Aout + (size_t)b * GN * GN;
#pragma unroll
  for (int ii = 0; ii < IPB; ++ii) {
    const int i = is + ii;
    const float x = acc[ii];
    const float sel = 1.f / (1.f + __expf(-fabsf(x)));
    const float lt  = __logf(sel + 1e-8f);
    float Aval = (x > 0.f) ? 1.f : 0.f;
    if (i == j) Aval = 1.f;     // diagonal: forced 1, excluded from log-sum
    else        logsum += lt;
    Abase[(size_t)i * GN + j] = Aval;   // lanes = consecutive j: coalesced
  }

  // Deterministic intra-block reduction (fixed shuffle-tree order).
#pragma unroll
  for (int off = 32; off > 0; off >>= 1)
    logsum += __shfl_down(logsum, off, 64);
  __shared__ float red[2];
  const int lane = threadIdx.x & 63;
  const int wid  = threadIdx.x >> 6;
  if (lane == 0) red[wid] = logsum;
  __syncthreads();
  // Transposed layout: consecutive b in consecutive addresses per q-slice.
  if (threadIdx.x == 0) part[q * GB + b] = red[0] + red[1];
}

// probs[b] = sum of the 64 slice partials, fixed order; each of the 64 loads
// is fully coalesced across the 64 threads (part is [ISPLIT][GB]).
__global__ __launch_bounds__(64) void glcn_reduce(
    const float* __restrict__ part, float* __restrict__ probs) {
  const int b = threadIdx.x;
  float s = 0.f;
#pragma unroll
  for (int q = 0; q < ISPLIT; ++q) s += part[q * GB + b];
  probs[b] = s;
}

extern "C" void kernel_launch(void* const* d_in, const int* in_sizes, int n_in,
                              void* d_out, int out_size, void* d_ws, size_t ws_size,
                              hipStream_t stream) {
  const float* h = (const float*)d_in[0];   // [64,128,80] f32
  const float* w = (const float*)d_in[1];   // [64,1] f32
  float* Aout  = (float*)d_out;                       // [64,128,128]
  float* probs = Aout + (size_t)GB * GN * GN;         // [64]
  float* part  = (float*)d_ws;                        // ISPLIT*GB floats

  glcn_main<<<GB * ISPLIT, 128, 0, stream>>>(h, w, Aout, part);
  glcn_reduce<<<1, 64, 0, stream>>>(part, probs);
}

// Round 10
// 15.887 us; speedup vs baseline: 1.1641x; 1.1641x over previous
//
#include <hip/hip_runtime.h>

#define GB 64
#define GN 128
#define F_OBS 64
#define F_TOT 80
#define ISPLIT 32
#define IPB (GN / ISPLIT)   // 4 i-rows per block

// R8's structure (best: 16.0us; occupancy sweet spot ISPLIT=32 per the
// 16/32/64 sweep). This round: "issue everything, wait once" -- explicit
// full prefetch of the own row (16 float4 back-to-back -> single vmcnt
// drain) + FULL kq unroll (all 64 scalar row loads hoisted into one batch
// on the SMEM pipe) to eliminate the 4 per-wave stall windows that
// 'unroll 4' left. Epilogue cheapened: log(sigmoid(|x|)+1e-8) ==
// -log(1+exp(-|x|)) to rel err <2e-8 -- saves the v_rcp per row.
//
// Standing lessons: no cross-block ordering (R2: 7x), no probs atomics /
// memset nodes (R5: +14us), partner rows on the scalar pipe only (R7:
// per-lane gathers = 8x HBM fetch), small acc + bounded live state (R4/R6),
// occupancy sweet spot 4 waves/SIMD at ISPLIT=32 (R8/R9).
__global__ __launch_bounds__(128, 4) void glcn_main(
    const float* __restrict__ h, const float* __restrict__ w,
    float* __restrict__ Aout, float* __restrict__ part) {
  const int blk = blockIdx.x;
  const int b  = blk >> 5;                    // / ISPLIT
  const int q  = blk & (ISPLIT - 1);          // i-split index
  const int is = q * IPB;                     // block-uniform
  const int j  = threadIdx.x;                 // 0..127

  const float* rowj = h + ((size_t)(b * GN + j)) * F_TOT;    // per-lane
  const float* rows = h + ((size_t)(b * GN + is)) * F_TOT;   // uniform->s_load

  // Prefetch the whole own row: 16 independent float4 loads in flight at
  // once (64 VGPR), ONE drain instead of 4 in-loop vmcnt stalls.
  float4 hj[F_OBS / 4];
#pragma unroll
  for (int kq = 0; kq < F_OBS / 4; ++kq)
    hj[kq] = *reinterpret_cast<const float4*>(rowj + 4 * kq);

  float acc[IPB];
#pragma unroll
  for (int ii = 0; ii < IPB; ++ii) acc[ii] = 0.f;

#pragma unroll
  for (int kq = 0; kq < F_OBS / 4; ++kq) {
    const float4 hv = hj[kq];
    const float4 wv = *reinterpret_cast<const float4*>(w + 4 * kq);  // scalar
#pragma unroll
    for (int ii = 0; ii < IPB; ++ii) {
      const float* ri = rows + ii * F_TOT + 4 * kq;   // scalar dwordx4
      acc[ii] = fmaf(wv.x, fabsf(hv.x - ri[0]), acc[ii]);
      acc[ii] = fmaf(wv.y, fabsf(hv.y - ri[1]), acc[ii]);
      acc[ii] = fmaf(wv.z, fabsf(hv.z - ri[2]), acc[ii]);
      acc[ii] = fmaf(wv.w, fabsf(hv.w - ri[3]), acc[ii]);
    }
  }

  // Epilogue. sigmoid(x)>0.5 <=> x>0; selected = A?y:(1-y) = sigmoid(|x|);
  // log(sigmoid(|x|)+1e-8) = -log(1+exp(-|x|)) + O(2e-8).
  float logsum = 0.f;
  float* Abase = Aout + (size_t)b * GN * GN;
#pragma unroll
  for (int ii = 0; ii < IPB; ++ii) {
    const int i = is + ii;
    const float x = acc[ii];
    const float lt = -__logf(1.f + __expf(-fabsf(x)));
    float Aval = (x > 0.f) ? 1.f : 0.f;
    if (i == j) Aval = 1.f;     // diagonal: forced 1, excluded from log-sum
    else        logsum += lt;
    Abase[(size_t)i * GN + j] = Aval;   // lanes = consecutive j: coalesced
  }

  // Deterministic intra-block reduction (fixed shuffle-tree order).
#pragma unroll
  for (int off = 32; off > 0; off >>= 1)
    logsum += __shfl_down(logsum, off, 64);
  __shared__ float red[2];
  const int lane = threadIdx.x & 63;
  const int wid  = threadIdx.x >> 6;
  if (lane == 0) red[wid] = logsum;
  __syncthreads();
  // Transposed layout: consecutive b in consecutive addresses per q-slice.
  if (threadIdx.x == 0) part[q * GB + b] = red[0] + red[1];
}

// probs[b] = sum of the 32 slice partials, fixed order; each of the 32 loads
// is fully coalesced across the 64 threads (part is [ISPLIT][GB]).
__global__ __launch_bounds__(64) void glcn_reduce(
    const float* __restrict__ part, float* __restrict__ probs) {
  const int b = threadIdx.x;
  float s = 0.f;
#pragma unroll
  for (int q = 0; q < ISPLIT; ++q) s += part[q * GB + b];
  probs[b] = s;
}

extern "C" void kernel_launch(void* const* d_in, const int* in_sizes, int n_in,
                              void* d_out, int out_size, void* d_ws, size_t ws_size,
                              hipStream_t stream) {
  const float* h = (const float*)d_in[0];   // [64,128,80] f32
  const float* w = (const float*)d_in[1];   // [64,1] f32
  float* Aout  = (float*)d_out;                       // [64,128,128]
  float* probs = Aout + (size_t)GB * GN * GN;         // [64]
  float* part  = (float*)d_ws;                        // ISPLIT*GB floats

  glcn_main<<<GB * ISPLIT, 128, 0, stream>>>(h, w, Aout, part);
  glcn_reduce<<<1, 64, 0, stream>>>(part, probs);
}